// Round 11
// baseline (35.936 us; speedup 1.0000x reference)
//
#include <hip/hip_runtime.h>
#include <math.h>

#define H 4096
#define D 104
#define CSTRIDE 32        // 32 uints = 128 B between counters / pred slots

typedef float f32x4 __attribute__((ext_vector_type(4)));

__device__ __forceinline__ float dot4(f32x4 a, f32x4 b) {
    return a.x * b.x + a.y * b.y + a.z * b.z + a.w * b.w;
}

// Kernel 1: h_t = sigmoid(Uw @ hidden + Ub + Ww @ line + Wb)
// Half-row per wave, 2048 blocks x 4 waves, 100% occupancy, NT loads
// (R9 config — best measured: 20.59 us total).
__global__ void __launch_bounds__(256, 8) k_hidden(
    const float* __restrict__ Uw, const float* __restrict__ hidden,
    const float* __restrict__ Ub, const float* __restrict__ Ww,
    const float* __restrict__ line, const float* __restrict__ Wb,
    float* __restrict__ h_out, unsigned* __restrict__ segcnt)
{
    __shared__ f32x4 s_h4[H / 4];          // 16 KB
    __shared__ float s_part[4];

    const int tid  = threadIdx.x;
    const int wave = tid >> 6;
    const int lane = tid & 63;
    const int g    = blockIdx.x * 4 + wave;   // global wave id, 0..8191
    const int row  = g >> 1;
    const int half = g & 1;

    if (blockIdx.x == 0 && tid < 10)
        __hip_atomic_store(&segcnt[tid * CSTRIDE], 0u,
                           __ATOMIC_RELAXED, __HIP_MEMORY_SCOPE_AGENT);

    // stage hidden to LDS (1024 f32x4 / 256 threads = 4 each)
    const f32x4* __restrict__ hv = (const f32x4*)hidden;
    #pragma unroll
    for (int i = tid; i < H / 4; i += 256)
        s_h4[i] = hv[i];
    __syncthreads();

    // this wave's half-row: 512 f32x4 starting at column-f32x4 c0
    const int c0 = half * (H / 8);            // 0 or 512 (f32x4 units)
    const f32x4* __restrict__ u = (const f32x4*)(Uw + (size_t)row * H) + c0;

    // issue all 8 streaming loads back-to-back
    f32x4 a0 = __builtin_nontemporal_load(&u[lane]);
    f32x4 a1 = __builtin_nontemporal_load(&u[lane + 64]);
    f32x4 a2 = __builtin_nontemporal_load(&u[lane + 128]);
    f32x4 a3 = __builtin_nontemporal_load(&u[lane + 192]);
    f32x4 a4 = __builtin_nontemporal_load(&u[lane + 256]);
    f32x4 a5 = __builtin_nontemporal_load(&u[lane + 320]);
    f32x4 a6 = __builtin_nontemporal_load(&u[lane + 384]);
    f32x4 a7 = __builtin_nontemporal_load(&u[lane + 448]);

    float acc0, acc1;
    {
        const f32x4* hb = s_h4 + c0;
        acc0  = dot4(a0, hb[lane]);
        acc1  = dot4(a1, hb[lane + 64]);
        acc0 += dot4(a2, hb[lane + 128]);
        acc1 += dot4(a3, hb[lane + 192]);
        acc0 += dot4(a4, hb[lane + 256]);
        acc1 += dot4(a5, hb[lane + 320]);
        acc0 += dot4(a6, hb[lane + 384]);
        acc1 += dot4(a7, hb[lane + 448]);
    }
    float acc = acc0 + acc1;

    // Ww @ line tail (26 f32x4/row): folded into the half==0 wave
    if (half == 0 && lane < D / 4) {
        const f32x4* __restrict__ w  = (const f32x4*)(Ww + (size_t)row * D);
        const f32x4* __restrict__ lv = (const f32x4*)line;
        f32x4 a = __builtin_nontemporal_load(&w[lane]);
        acc += dot4(a, lv[lane]);
    }

    #pragma unroll
    for (int off = 32; off; off >>= 1)
        acc += __shfl_down(acc, off, 64);

    if (lane == 0) s_part[wave] = acc;
    __syncthreads();

    // half==0 wave of each row finishes: combine halves, bias, sigmoid
    if (half == 0 && lane == 0) {
        float v = s_part[wave] + s_part[wave + 1] + Ub[row] + Wb[row];
        h_out[row] = 1.f / (1.f + expf(-v));
    }
}

// Kernel 2 (merged): one block per pred row; last-arriving block per
// segment does the log_softmax (atomic return value, no spinning).
__global__ void __launch_bounds__(256) k_pred(
    const float* __restrict__ Vw, const float* __restrict__ h_t,
    const float* __restrict__ Vb, float* __restrict__ out,
    unsigned* __restrict__ segcnt, float* __restrict__ pred)
{
    __shared__ float r[4];
    __shared__ int s_last;
    const int bid  = blockIdx.x;
    const int tid  = threadIdx.x;
    const int wave = tid >> 6;
    const int lane = tid & 63;

    const f32x4* __restrict__ v  = (const f32x4*)(Vw + (size_t)bid * H);
    const f32x4* __restrict__ hv = (const f32x4*)h_t;

    float acc = 0.f;
    #pragma unroll
    for (int j4 = tid; j4 < H / 4; j4 += 256) {   // 4 iterations
        f32x4 x = __builtin_nontemporal_load(&v[j4]);
        f32x4 y = hv[j4];
        acc += dot4(x, y);
    }
    #pragma unroll
    for (int off = 32; off; off >>= 1)
        acc += __shfl_down(acc, off, 64);
    if (lane == 0) r[wave] = acc;
    __syncthreads();

    // segment lookup (block-uniform)
    const int SEG[11] = {0, 13, 26, 39, 48, 52, 65, 78, 91, 100, 104};
    int sidx = 0;
    #pragma unroll
    for (int i = 1; i < 10; ++i)
        if (bid >= SEG[i]) sidx = i;
    const int a   = SEG[sidx];
    const int len = SEG[sidx + 1] - a;

    if (tid == 0) {
        float pr = r[0] + r[1] + r[2] + r[3] + Vb[bid];
        __hip_atomic_store(&pred[bid * CSTRIDE], pr,
                           __ATOMIC_RELAXED, __HIP_MEMORY_SCOPE_AGENT);
        asm volatile("s_waitcnt vmcnt(0)" ::: "memory");  // pred at LLC
        unsigned old = __hip_atomic_fetch_add(&segcnt[sidx * CSTRIDE], 1u,
                                              __ATOMIC_RELAXED,
                                              __HIP_MEMORY_SCOPE_AGENT);
        s_last = (old == (unsigned)(len - 1));
    }
    __syncthreads();

    // last-arriving block of the segment: all peers' preds are at the LLC
    if (s_last && wave == 0) {
        float x = -INFINITY;
        if (lane < len)
            x = __hip_atomic_load(&pred[(a + lane) * CSTRIDE],
                                  __ATOMIC_RELAXED, __HIP_MEMORY_SCOPE_AGENT);
        float m = x;
        #pragma unroll
        for (int off = 32; off; off >>= 1)
            m = fmaxf(m, __shfl_xor(m, off, 64));
        float e = (lane < len) ? expf(x - m) : 0.f;
        float ssum = e;
        #pragma unroll
        for (int off = 32; off; off >>= 1)
            ssum += __shfl_xor(ssum, off, 64);
        if (lane < len) out[a + lane] = x - m - logf(ssum);
    }
}

extern "C" void kernel_launch(void* const* d_in, const int* in_sizes, int n_in,
                              void* d_out, int out_size, void* d_ws, size_t ws_size,
                              hipStream_t stream) {
    const float* line   = (const float*)d_in[0];
    const float* hidden = (const float*)d_in[1];
    const float* Uw     = (const float*)d_in[2];
    const float* Ub     = (const float*)d_in[3];
    const float* Ww     = (const float*)d_in[4];
    const float* Wb     = (const float*)d_in[5];
    const float* Vw     = (const float*)d_in[6];
    const float* Vb     = (const float*)d_in[7];

    float* out = (float*)d_out;       // [0:104) pred_logsoft, [104:4200) h_t
    float* h_t = out + D;

    unsigned* segcnt = (unsigned*)d_ws;            // 10 counters, 128B stride
    float*    pred   = (float*)d_ws + 1024;        // 104 slots, 128B stride

    // DIAGNOSTIC ROUND: run the full (idempotent) sequence TWICE in the
    // graph. dur2x - dur1x = true kernel sum; 2*dur1x - dur2x = fixed
    // per-replay overhead F. Output is identical (stores rewrite the same
    // values; k1 block 0 re-zeroes segcnt before the second k_pred).
    k_hidden<<<H / 2, 256, 0, stream>>>(Uw, hidden, Ub, Ww, line, Wb, h_t, segcnt);
    k_pred<<<D, 256, 0, stream>>>(Vw, h_t, Vb, out, segcnt, pred);
    k_hidden<<<H / 2, 256, 0, stream>>>(Uw, hidden, Ub, Ww, line, Wb, h_t, segcnt);
    k_pred<<<D, 256, 0, stream>>>(Vw, h_t, Vb, out, segcnt, pred);
}

// Round 12
// 20.416 us; speedup vs baseline: 1.7602x; 1.7602x over previous
//
#include <hip/hip_runtime.h>
#include <math.h>

#define H 4096
#define D 104
#define CSTRIDE 32        // 32 uints = 128 B between counters / pred slots

typedef float f32x4 __attribute__((ext_vector_type(4)));

__device__ __forceinline__ float dot4(f32x4 a, f32x4 b) {
    return a.x * b.x + a.y * b.y + a.z * b.z + a.w * b.w;
}

// Kernel 1: h_t = sigmoid(Uw @ hidden + Ub + Ww @ line + Wb)
// Half-row per wave, 2048 blocks x 4 waves, 100% occupancy, NT loads.
// Best-measured config (R9): 20.59 us total. k1 runs at ~5.1 TB/s read,
// the empirically-established pure-read ceiling for this access pattern
// (4 orthogonal structures all land at 4.6-5.1 TB/s; write BW 6.8 TB/s is
// not a valid read ceiling - no MSHR pressure on stores).
__global__ void __launch_bounds__(256, 8) k_hidden(
    const float* __restrict__ Uw, const float* __restrict__ hidden,
    const float* __restrict__ Ub, const float* __restrict__ Ww,
    const float* __restrict__ line, const float* __restrict__ Wb,
    float* __restrict__ h_out, unsigned* __restrict__ segcnt)
{
    __shared__ f32x4 s_h4[H / 4];          // 16 KB
    __shared__ float s_part[4];

    const int tid  = threadIdx.x;
    const int wave = tid >> 6;
    const int lane = tid & 63;
    const int g    = blockIdx.x * 4 + wave;   // global wave id, 0..8191
    const int row  = g >> 1;
    const int half = g & 1;

    if (blockIdx.x == 0 && tid < 10)
        __hip_atomic_store(&segcnt[tid * CSTRIDE], 0u,
                           __ATOMIC_RELAXED, __HIP_MEMORY_SCOPE_AGENT);

    // stage hidden to LDS (1024 f32x4 / 256 threads = 4 each)
    const f32x4* __restrict__ hv = (const f32x4*)hidden;
    #pragma unroll
    for (int i = tid; i < H / 4; i += 256)
        s_h4[i] = hv[i];
    __syncthreads();

    // this wave's half-row: 512 f32x4 starting at column-f32x4 c0
    const int c0 = half * (H / 8);            // 0 or 512 (f32x4 units)
    const f32x4* __restrict__ u = (const f32x4*)(Uw + (size_t)row * H) + c0;

    // issue all 8 streaming loads back-to-back
    f32x4 a0 = __builtin_nontemporal_load(&u[lane]);
    f32x4 a1 = __builtin_nontemporal_load(&u[lane + 64]);
    f32x4 a2 = __builtin_nontemporal_load(&u[lane + 128]);
    f32x4 a3 = __builtin_nontemporal_load(&u[lane + 192]);
    f32x4 a4 = __builtin_nontemporal_load(&u[lane + 256]);
    f32x4 a5 = __builtin_nontemporal_load(&u[lane + 320]);
    f32x4 a6 = __builtin_nontemporal_load(&u[lane + 384]);
    f32x4 a7 = __builtin_nontemporal_load(&u[lane + 448]);

    float acc0, acc1;
    {
        const f32x4* hb = s_h4 + c0;
        acc0  = dot4(a0, hb[lane]);
        acc1  = dot4(a1, hb[lane + 64]);
        acc0 += dot4(a2, hb[lane + 128]);
        acc1 += dot4(a3, hb[lane + 192]);
        acc0 += dot4(a4, hb[lane + 256]);
        acc1 += dot4(a5, hb[lane + 320]);
        acc0 += dot4(a6, hb[lane + 384]);
        acc1 += dot4(a7, hb[lane + 448]);
    }
    float acc = acc0 + acc1;

    // Ww @ line tail (26 f32x4/row): folded into the half==0 wave
    if (half == 0 && lane < D / 4) {
        const f32x4* __restrict__ w  = (const f32x4*)(Ww + (size_t)row * D);
        const f32x4* __restrict__ lv = (const f32x4*)line;
        f32x4 a = __builtin_nontemporal_load(&w[lane]);
        acc += dot4(a, lv[lane]);
    }

    #pragma unroll
    for (int off = 32; off; off >>= 1)
        acc += __shfl_down(acc, off, 64);

    if (lane == 0) s_part[wave] = acc;
    __syncthreads();

    // half==0 wave of each row finishes: combine halves, bias, sigmoid
    if (half == 0 && lane == 0) {
        float v = s_part[wave] + s_part[wave + 1] + Ub[row] + Wb[row];
        h_out[row] = 1.f / (1.f + expf(-v));
    }
}

// Kernel 2 (merged): one block per pred row; last-arriving block per
// segment does the log_softmax (atomic return value, no spinning).
__global__ void __launch_bounds__(256) k_pred(
    const float* __restrict__ Vw, const float* __restrict__ h_t,
    const float* __restrict__ Vb, float* __restrict__ out,
    unsigned* __restrict__ segcnt, float* __restrict__ pred)
{
    __shared__ float r[4];
    __shared__ int s_last;
    const int bid  = blockIdx.x;
    const int tid  = threadIdx.x;
    const int wave = tid >> 6;
    const int lane = tid & 63;

    const f32x4* __restrict__ v  = (const f32x4*)(Vw + (size_t)bid * H);
    const f32x4* __restrict__ hv = (const f32x4*)h_t;

    float acc = 0.f;
    #pragma unroll
    for (int j4 = tid; j4 < H / 4; j4 += 256) {   // 4 iterations
        f32x4 x = __builtin_nontemporal_load(&v[j4]);
        f32x4 y = hv[j4];
        acc += dot4(x, y);
    }
    #pragma unroll
    for (int off = 32; off; off >>= 1)
        acc += __shfl_down(acc, off, 64);
    if (lane == 0) r[wave] = acc;
    __syncthreads();

    // segment lookup (block-uniform)
    const int SEG[11] = {0, 13, 26, 39, 48, 52, 65, 78, 91, 100, 104};
    int sidx = 0;
    #pragma unroll
    for (int i = 1; i < 10; ++i)
        if (bid >= SEG[i]) sidx = i;
    const int a   = SEG[sidx];
    const int len = SEG[sidx + 1] - a;

    if (tid == 0) {
        float pr = r[0] + r[1] + r[2] + r[3] + Vb[bid];
        __hip_atomic_store(&pred[bid * CSTRIDE], pr,
                           __ATOMIC_RELAXED, __HIP_MEMORY_SCOPE_AGENT);
        asm volatile("s_waitcnt vmcnt(0)" ::: "memory");  // pred at LLC
        unsigned old = __hip_atomic_fetch_add(&segcnt[sidx * CSTRIDE], 1u,
                                              __ATOMIC_RELAXED,
                                              __HIP_MEMORY_SCOPE_AGENT);
        s_last = (old == (unsigned)(len - 1));
    }
    __syncthreads();

    // last-arriving block of the segment: all peers' preds are at the LLC
    if (s_last && wave == 0) {
        float x = -INFINITY;
        if (lane < len)
            x = __hip_atomic_load(&pred[(a + lane) * CSTRIDE],
                                  __ATOMIC_RELAXED, __HIP_MEMORY_SCOPE_AGENT);
        float m = x;
        #pragma unroll
        for (int off = 32; off; off >>= 1)
            m = fmaxf(m, __shfl_xor(m, off, 64));
        float e = (lane < len) ? expf(x - m) : 0.f;
        float ssum = e;
        #pragma unroll
        for (int off = 32; off; off >>= 1)
            ssum += __shfl_xor(ssum, off, 64);
        if (lane < len) out[a + lane] = x - m - logf(ssum);
    }
}

extern "C" void kernel_launch(void* const* d_in, const int* in_sizes, int n_in,
                              void* d_out, int out_size, void* d_ws, size_t ws_size,
                              hipStream_t stream) {
    const float* line   = (const float*)d_in[0];
    const float* hidden = (const float*)d_in[1];
    const float* Uw     = (const float*)d_in[2];
    const float* Ub     = (const float*)d_in[3];
    const float* Ww     = (const float*)d_in[4];
    const float* Wb     = (const float*)d_in[5];
    const float* Vw     = (const float*)d_in[6];
    const float* Vb     = (const float*)d_in[7];

    float* out = (float*)d_out;       // [0:104) pred_logsoft, [104:4200) h_t
    float* h_t = out + D;

    unsigned* segcnt = (unsigned*)d_ws;            // 10 counters, 128B stride
    float*    pred   = (float*)d_ws + 1024;        // 104 slots, 128B stride

    k_hidden<<<H / 2, 256, 0, stream>>>(Uw, hidden, Ub, Ww, line, Wb, h_t, segcnt);
    k_pred<<<D, 256, 0, stream>>>(Vw, h_t, Vb, out, segcnt, pred);
}